// Round 1
// baseline (2667.176 us; speedup 1.0000x reference)
//
#include <hip/hip_runtime.h>

#define NDIS 5000
#define NGEN 20000
#define NTOT 25000
#define EDG  400000
#define EMB  128
#define HID  64

// ---------------- GEMM: C[M,128] (+)= scale * op(A) @ B (+ scale*bias) ----------------
// transA=0: A is [M,K] row-major. transA=1: A is [K,M] row-major (C = A^T @ B).
__global__ __launch_bounds__(256) void gemm128(
    const float* __restrict__ A, const float* __restrict__ B,
    float* __restrict__ C, const float* __restrict__ bias,
    int M, int K, float scale, int accumulate, int transA)
{
    __shared__ float As[16][64];   // [k][m]
    __shared__ float Bs[16][128];  // [k][n]
    const int tid = threadIdx.x;
    const int block_row = blockIdx.x * 64;
    const int tx = tid & 15;   // cols tx*8 .. tx*8+7
    const int ty = tid >> 4;   // rows ty*4 .. ty*4+3
    float acc[4][8];
#pragma unroll
    for (int i = 0; i < 4; ++i)
#pragma unroll
        for (int j = 0; j < 8; ++j) acc[i][j] = 0.f;

    for (int k0 = 0; k0 < K; k0 += 16) {
        // ---- stage A tile (64 rows x 16 k) ----
        if (!transA) {
            int row = tid >> 2;
            int kq  = (tid & 3) * 4;
            int gr  = block_row + row;
#pragma unroll
            for (int i = 0; i < 4; ++i) {
                int k = k0 + kq + i;
                float v = 0.f;
                if (gr < M && k < K) v = A[(size_t)gr * K + k];
                As[kq + i][row] = v;
            }
        } else {
            int ioff = tid & 63;
            int kq   = (tid >> 6) * 4;
            int gi   = block_row + ioff;
#pragma unroll
            for (int i = 0; i < 4; ++i) {
                int k = k0 + kq + i;
                float v = 0.f;
                if (gi < M && k < K) v = A[(size_t)k * M + gi];
                As[kq + i][ioff] = v;
            }
        }
        // ---- stage B tile (16 k x 128 n) ----
        {
            int col = (tid & 31) * 4;
            int kr  = tid >> 5;  // 0..7
#pragma unroll
            for (int p = 0; p < 2; ++p) {
                int k = k0 + kr + p * 8;
                float4 v = make_float4(0.f, 0.f, 0.f, 0.f);
                if (k < K) v = *reinterpret_cast<const float4*>(&B[(size_t)k * 128 + col]);
                *reinterpret_cast<float4*>(&Bs[kr + p * 8][col]) = v;
            }
        }
        __syncthreads();
#pragma unroll
        for (int kk = 0; kk < 16; ++kk) {
            float4 a  = *reinterpret_cast<const float4*>(&As[kk][ty * 4]);
            float4 b0 = *reinterpret_cast<const float4*>(&Bs[kk][tx * 8]);
            float4 b1 = *reinterpret_cast<const float4*>(&Bs[kk][tx * 8 + 4]);
            float av[4] = {a.x, a.y, a.z, a.w};
            float bv[8] = {b0.x, b0.y, b0.z, b0.w, b1.x, b1.y, b1.z, b1.w};
#pragma unroll
            for (int i = 0; i < 4; ++i)
#pragma unroll
                for (int j = 0; j < 8; ++j)
                    acc[i][j] = fmaf(av[i], bv[j], acc[i][j]);
        }
        __syncthreads();
    }
    // ---- epilogue ----
#pragma unroll
    for (int i = 0; i < 4; ++i) {
        int gr = block_row + ty * 4 + i;
        if (gr >= M) continue;
        float* Crow = C + (size_t)gr * 128 + tx * 8;
#pragma unroll
        for (int j = 0; j < 8; ++j) {
            float v = scale * acc[i][j];
            if (bias) v += scale * bias[tx * 8 + j];
            if (accumulate) v += Crow[j];
            Crow[j] = v;
        }
    }
}

// ---------------- CSR build ----------------
__global__ void k_deg(const int* __restrict__ dst, int* __restrict__ deg, int E) {
    int e = blockIdx.x * blockDim.x + threadIdx.x;
    if (e < E) atomicAdd(&deg[dst[e]], 1);
}

__global__ __launch_bounds__(1024) void k_scan(const int* __restrict__ deg,
                                               int* __restrict__ row_start,
                                               int* __restrict__ cursor, int n) {
    __shared__ int buf[1024];
    __shared__ int carry_s;
    int t = threadIdx.x;
    if (t == 0) { carry_s = 0; row_start[0] = 0; }
    __syncthreads();
    for (int base = 0; base < n; base += 1024) {
        int i = base + t;
        int v = (i < n) ? deg[i] : 0;
        buf[t] = v;
        __syncthreads();
        for (int off = 1; off < 1024; off <<= 1) {
            int add = (t >= off) ? buf[t - off] : 0;
            __syncthreads();
            buf[t] += add;
            __syncthreads();
        }
        int incl = buf[t] + carry_s;
        if (i < n) { row_start[i + 1] = incl; cursor[i] = incl - v; }
        __syncthreads();
        if (t == 1023) carry_s = incl;
        __syncthreads();
    }
}

__global__ void k_fill(const int* __restrict__ src, const int* __restrict__ dst,
                       int* __restrict__ cursor, int* __restrict__ esrc, int E) {
    int e = blockIdx.x * blockDim.x + threadIdx.x;
    if (e < E) {
        int pos = atomicAdd(&cursor[dst[e]], 1);
        esrc[pos] = src[e];
    }
}

// ---------------- SAGE projection: P = h@Ws (+b), Q = h@Wn ----------------
__global__ __launch_bounds__(256) void k_proj(const float* __restrict__ h, int Kdim,
                                              const float* __restrict__ Ws,
                                              const float* __restrict__ Wn,
                                              const float* __restrict__ b,
                                              float* __restrict__ P, float* __restrict__ Q,
                                              int Mrows)
{
    int row  = blockIdx.x * 2 + (threadIdx.x >> 7);
    int c128 = threadIdx.x & 127;
    if (row >= Mrows) return;
    int isQ = c128 >> 6;       // wave-uniform
    int c   = c128 & 63;
    const float* W = isQ ? Wn : Ws;
    const float* hr = h + (size_t)row * Kdim;
    float acc = isQ ? 0.f : b[c];
    for (int k = 0; k < Kdim; ++k)
        acc = fmaf(hr[k], W[k * 64 + c], acc);
    if (isQ) Q[(size_t)row * 64 + c] = acc;
    else     P[(size_t)row * 64 + c] = acc;
}

// ---------------- aggregate mean of Q over in-neighbors + combine ----------------
__global__ __launch_bounds__(64) void k_agg(const float* __restrict__ Q,
                                            const float* __restrict__ P,
                                            const int* __restrict__ rs,
                                            const int* __restrict__ esrc,
                                            float* __restrict__ out, int relu)
{
    int n = blockIdx.x, t = threadIdx.x;
    int s0 = rs[n], s1 = rs[n + 1];
    float s = 0.f;
    for (int i = s0; i < s1; ++i)
        s += Q[(size_t)esrc[i] * 64 + t];
    float dg = (float)(s1 - s0);
    s /= fmaxf(dg, 1.f);
    float v = P[(size_t)n * 64 + t] + s;
    if (relu) v = fmaxf(v, 0.f);
    out[(size_t)n * 64 + t] = v;
}

extern "C" void kernel_launch(void* const* d_in, const int* in_sizes, int n_in,
                              void* d_out, int out_size, void* d_ws, size_t ws_size,
                              hipStream_t stream)
{
    const float* d_features = (const float*)d_in[0];
    const float* g_features = (const float*)d_in[1];
    const float* miRNA_dis  = (const float*)d_in[2];
    const float* gene_dis   = (const float*)d_in[3];
    const float* Wd  = (const float*)d_in[4];
    const float* bd  = (const float*)d_in[5];
    const float* Wg  = (const float*)d_in[6];
    const float* bg  = (const float*)d_in[7];
    const float* W1  = (const float*)d_in[8];
    const float* W4  = (const float*)d_in[9];
    const float* Ws1 = (const float*)d_in[10];
    const float* Wn1 = (const float*)d_in[11];
    const float* b1  = (const float*)d_in[12];
    const float* Ws2 = (const float*)d_in[13];
    const float* Wn2 = (const float*)d_in[14];
    const float* b2  = (const float*)d_in[15];
    const int* src = (const int*)d_in[16];
    const int* dst = (const int*)d_in[17];
    (void)in_sizes; (void)n_in; (void)out_size; (void)ws_size;

    char* ws = (char*)d_ws;
    size_t off = 0;
    auto alloc = [&](size_t bytes) {
        void* p = ws + off;
        off = (off + bytes + 255) & ~(size_t)255;
        return p;
    };
    float* h0 = (float*)alloc((size_t)NTOT * EMB * 4);
    float* P  = (float*)alloc((size_t)NTOT * HID * 4);
    float* Q  = (float*)alloc((size_t)NTOT * HID * 4);
    float* h1 = (float*)alloc((size_t)NTOT * HID * 4);
    int* deg       = (int*)alloc((size_t)NTOT * 4);
    int* row_start = (int*)alloc((size_t)(NTOT + 1) * 4);
    int* cursor    = (int*)alloc((size_t)NTOT * 4);
    int* esrc      = (int*)alloc((size_t)EDG * 4);

    // ---- CSR by dst ----
    hipMemsetAsync(deg, 0, (size_t)NTOT * 4, stream);
    k_deg<<<(EDG + 255) / 256, 256, 0, stream>>>(dst, deg, EDG);
    k_scan<<<1, 1024, 0, stream>>>(deg, row_start, cursor, NTOT);
    k_fill<<<(EDG + 255) / 256, 256, 0, stream>>>(src, dst, cursor, esrc, EDG);

    // ---- node embeddings h0 = concat(h_dis, h_gen) ----
    gemm128<<<(NDIS + 63) / 64, 256, 0, stream>>>(d_features, Wd, h0, bd, NDIS, 383, 0.9f, 0, 0);
    gemm128<<<(NDIS + 63) / 64, 256, 0, stream>>>(miRNA_dis, W1, h0, nullptr, NDIS, 2000, 0.1f, 1, 1);
    gemm128<<<(NGEN + 63) / 64, 256, 0, stream>>>(g_features, Wg, h0 + (size_t)NDIS * EMB, bg, NGEN, 4395, 0.9f, 0, 0);
    gemm128<<<(NGEN + 63) / 64, 256, 0, stream>>>(gene_dis, W4, h0 + (size_t)NDIS * EMB, nullptr, NGEN, 5000, 0.1f, 1, 0);

    // ---- SAGE layer 1 (project to 64, then mean-aggregate) ----
    k_proj<<<NTOT / 2, 256, 0, stream>>>(h0, EMB, Ws1, Wn1, b1, P, Q, NTOT);
    k_agg<<<NTOT, 64, 0, stream>>>(Q, P, row_start, esrc, h1, 1);

    // ---- SAGE layer 2 ----
    k_proj<<<NTOT / 2, 256, 0, stream>>>(h1, HID, Ws2, Wn2, b2, P, Q, NTOT);
    k_agg<<<NTOT, 64, 0, stream>>>(Q, P, row_start, esrc, (float*)d_out, 0);
}

// Round 2
// 735.046 us; speedup vs baseline: 3.6286x; 3.6286x over previous
//
#include <hip/hip_runtime.h>

#define NDIS 5000
#define NGEN 20000
#define NTOT 25000
#define EDG  400000
#define EMB  128
#define HID  64

typedef __attribute__((ext_vector_type(8))) short short8;
typedef __attribute__((ext_vector_type(4))) float f32x4;
typedef __attribute__((ext_vector_type(4), aligned(4))) float f32x4u;

__device__ __forceinline__ ushort f2bf(float f) {
    unsigned u = __float_as_uint(f);
    u += 0x7fffu + ((u >> 16) & 1u);
    return (ushort)(u >> 16);
}

__device__ __forceinline__ void MFMA(f32x4& d, short8 a, short8 b) {
    asm volatile("v_mfma_f32_16x16x32_bf16 %0, %1, %2, %0"
                 : "+v"(d) : "v"(a), "v"(b));
}

// ---------------- transpose + f32->bf16 convert: in[R][C] f32 -> out[C][Rp] bf16 ----------------
__global__ __launch_bounds__(256) void k_tcvt(const float* __restrict__ in,
                                              ushort* __restrict__ out,
                                              int R, int C, int Rp)
{
    __shared__ float t[32][33];
    int tx = threadIdx.x & 31, ty = threadIdx.x >> 5;
    int c0 = blockIdx.x * 32, r0 = blockIdx.y * 32;
#pragma unroll
    for (int j = 0; j < 4; ++j) {
        int r = r0 + ty + j * 8, c = c0 + tx;
        t[ty + j * 8][tx] = (r < R && c < C) ? in[(size_t)r * C + c] : 0.f;
    }
    __syncthreads();
#pragma unroll
    for (int j = 0; j < 4; ++j) {
        int c = c0 + ty + j * 8, r = r0 + tx;
        if (c < C && r < R) out[(size_t)c * Rp + r] = f2bf(t[tx][ty + j * 8]);
    }
}

// ---------------- MFMA GEMM: C[M,128] += scale * A[M,K] @ Bt[128,K]^T ----------------
// A is f32 (AF32=1, converted to bf16 during staging) or bf16 (AF32=0).
// Bt is bf16 [128][ldB] (pre-transposed weight). Split-K over gridDim.y, f32 atomics into C.
template<bool AF32>
__global__ __launch_bounds__(256) void mfma_gemm(
    const void* __restrict__ Av, const ushort* __restrict__ Bt,
    float* __restrict__ C, int M, int K, int ldB, float scale)
{
    __shared__ ushort Alds[64 * 40];   // 64 rows x 32k, padded to 40
    __shared__ ushort Blds[128 * 40];  // 128 n-rows x 32k, padded to 40
    const int tid  = threadIdx.x;
    const int lane = tid & 63;
    const int w    = tid >> 6;
    const int wr = w >> 1, wc = w & 1;     // 2x2 waves over 64x128 tile
    const int bm0 = blockIdx.x * 64;
    const int ar = tid >> 2, aq = tid & 3; // A staging: 4 thr/row, 8 k each
    const int br = tid >> 1, bh = tid & 1; // B staging: 2 thr/row, 16 k each

    const int ktiles = (K + 31) >> 5;
    const int per = (ktiles + gridDim.y - 1) / gridDim.y;
    const int kt0 = blockIdx.y * per;
    const int kt1 = min(ktiles, kt0 + per);
    if (kt0 >= kt1) return;

    f32x4 acc[2][4];
#pragma unroll
    for (int i = 0; i < 2; ++i)
#pragma unroll
        for (int j = 0; j < 4; ++j) acc[i][j] = {0.f, 0.f, 0.f, 0.f};

    const int arow = bm0 + ar;
    for (int kt = kt0; kt < kt1; ++kt) {
        const int kk = kt << 5;
        const bool full = (kk + 32 <= K);
        // ---- stage A tile ----
        {
            short8 s = {0, 0, 0, 0, 0, 0, 0, 0};
            if (AF32) {
                const float* A = (const float*)Av;
                if (arow < M) {
                    const float* p = A + (size_t)arow * K + kk + aq * 8;
                    float f[8];
                    if (full) {
                        f32x4u v0 = *(const f32x4u*)p;
                        f32x4u v1 = *(const f32x4u*)(p + 4);
#pragma unroll
                        for (int e = 0; e < 4; ++e) { f[e] = v0[e]; f[4 + e] = v1[e]; }
                    } else {
#pragma unroll
                        for (int e = 0; e < 8; ++e) {
                            int k = kk + aq * 8 + e;
                            f[e] = (k < K) ? p[e] : 0.f;
                        }
                    }
#pragma unroll
                    for (int e = 0; e < 8; ++e) s[e] = (short)f2bf(f[e]);
                }
            } else {
                const ushort* A = (const ushort*)Av;
                if (arow < M) {
                    const ushort* p = A + (size_t)arow * K + kk + aq * 8;
                    if (full) {
                        s = *(const short8*)p;
                    } else {
#pragma unroll
                        for (int e = 0; e < 8; ++e) {
                            int k = kk + aq * 8 + e;
                            if (k < K) s[e] = (short)p[e];
                        }
                    }
                }
            }
            *(short8*)&Alds[ar * 40 + aq * 8] = s;
        }
        // ---- stage B tile ----
        {
            short8 s0 = {0, 0, 0, 0, 0, 0, 0, 0}, s1 = s0;
            const ushort* p = Bt + (size_t)br * ldB + kk + bh * 16;
            if (full) {
                s0 = *(const short8*)p;
                s1 = *(const short8*)(p + 8);
            } else {
#pragma unroll
                for (int e = 0; e < 8; ++e) {
                    int k = kk + bh * 16 + e;
                    if (k < K)     s0[e] = (short)p[e];
                    if (k + 8 < K) s1[e] = (short)p[e + 8];
                }
            }
            *(short8*)&Blds[br * 40 + bh * 16] = s0;
            *(short8*)&Blds[br * 40 + bh * 16 + 8] = s1;
        }
        __syncthreads();
        // ---- fragments + 8 MFMA ----
        {
            const int fr = lane & 15, kg = (lane >> 4) * 8;
            short8 a0 = *(const short8*)&Alds[(wr * 32 + fr) * 40 + kg];
            short8 a1 = *(const short8*)&Alds[(wr * 32 + 16 + fr) * 40 + kg];
            short8 b0 = *(const short8*)&Blds[(wc * 64 + fr) * 40 + kg];
            short8 b1 = *(const short8*)&Blds[(wc * 64 + 16 + fr) * 40 + kg];
            short8 b2 = *(const short8*)&Blds[(wc * 64 + 32 + fr) * 40 + kg];
            short8 b3 = *(const short8*)&Blds[(wc * 64 + 48 + fr) * 40 + kg];
            MFMA(acc[0][0], a0, b0); MFMA(acc[0][1], a0, b1);
            MFMA(acc[0][2], a0, b2); MFMA(acc[0][3], a0, b3);
            MFMA(acc[1][0], a1, b0); MFMA(acc[1][1], a1, b1);
            MFMA(acc[1][2], a1, b2); MFMA(acc[1][3], a1, b3);
        }
        __syncthreads();
    }
    asm volatile("s_nop 7\n\ts_nop 7\n\ts_nop 7" ::: "memory"); // MFMA->VALU hazard guard
    // ---- epilogue: atomic f32 accumulate (C pre-zeroed; bias added separately) ----
    const int fr = lane & 15, fq = lane >> 4;
#pragma unroll
    for (int mi = 0; mi < 2; ++mi)
#pragma unroll
        for (int ni = 0; ni < 4; ++ni)
#pragma unroll
            for (int r = 0; r < 4; ++r) {
                int row = bm0 + wr * 32 + mi * 16 + fq * 4 + r;
                if (row < M) {
                    int col = wc * 64 + ni * 16 + fr;
                    atomicAdd(&C[(size_t)row * 128 + col], scale * acc[mi][ni][r]);
                }
            }
}

__global__ void k_bias(float* __restrict__ h, const float* __restrict__ bd,
                       const float* __restrict__ bg) {
    int i = blockIdx.x * 256 + threadIdx.x;
    if (i >= NTOT * EMB) return;
    int col = i & 127;
    h[i] += 0.9f * ((i >> 7) < NDIS ? bd[col] : bg[col]);
}

// ---------------- CSR build ----------------
__global__ void k_deg(const int* __restrict__ dst, int* __restrict__ deg, int E) {
    int e = blockIdx.x * blockDim.x + threadIdx.x;
    if (e < E) atomicAdd(&deg[dst[e]], 1);
}

__global__ __launch_bounds__(1024) void k_scan(const int* __restrict__ deg,
                                               int* __restrict__ row_start,
                                               int* __restrict__ cursor, int n) {
    __shared__ int buf[1024];
    __shared__ int carry_s;
    int t = threadIdx.x;
    if (t == 0) { carry_s = 0; row_start[0] = 0; }
    __syncthreads();
    for (int base = 0; base < n; base += 1024) {
        int i = base + t;
        int v = (i < n) ? deg[i] : 0;
        buf[t] = v;
        __syncthreads();
        for (int off = 1; off < 1024; off <<= 1) {
            int add = (t >= off) ? buf[t - off] : 0;
            __syncthreads();
            buf[t] += add;
            __syncthreads();
        }
        int incl = buf[t] + carry_s;
        if (i < n) { row_start[i + 1] = incl; cursor[i] = incl - v; }
        __syncthreads();
        if (t == 1023) carry_s = incl;
        __syncthreads();
    }
}

__global__ void k_fill(const int* __restrict__ src, const int* __restrict__ dst,
                       int* __restrict__ cursor, int* __restrict__ esrc, int E) {
    int e = blockIdx.x * blockDim.x + threadIdx.x;
    if (e < E) {
        int pos = atomicAdd(&cursor[dst[e]], 1);
        esrc[pos] = src[e];
    }
}

// ---------------- SAGE projection: P = h@Ws (+b), Q = h@Wn ----------------
__global__ __launch_bounds__(256) void k_proj(const float* __restrict__ h, int Kdim,
                                              const float* __restrict__ Ws,
                                              const float* __restrict__ Wn,
                                              const float* __restrict__ b,
                                              float* __restrict__ P, float* __restrict__ Q,
                                              int Mrows)
{
    int row  = blockIdx.x * 2 + (threadIdx.x >> 7);
    int c128 = threadIdx.x & 127;
    if (row >= Mrows) return;
    int isQ = c128 >> 6;
    int c   = c128 & 63;
    const float* W = isQ ? Wn : Ws;
    const float* hr = h + (size_t)row * Kdim;
    float acc = isQ ? 0.f : b[c];
    for (int k = 0; k < Kdim; ++k)
        acc = fmaf(hr[k], W[k * 64 + c], acc);
    if (isQ) Q[(size_t)row * 64 + c] = acc;
    else     P[(size_t)row * 64 + c] = acc;
}

// ---------------- aggregate mean of Q over in-neighbors + combine ----------------
__global__ __launch_bounds__(64) void k_agg(const float* __restrict__ Q,
                                            const float* __restrict__ P,
                                            const int* __restrict__ rs,
                                            const int* __restrict__ esrc,
                                            float* __restrict__ out, int relu)
{
    int n = blockIdx.x, t = threadIdx.x;
    int s0 = rs[n], s1 = rs[n + 1];
    float s = 0.f;
    for (int i = s0; i < s1; ++i)
        s += Q[(size_t)esrc[i] * 64 + t];
    float dg = (float)(s1 - s0);
    s /= fmaxf(dg, 1.f);
    float v = P[(size_t)n * 64 + t] + s;
    if (relu) v = fmaxf(v, 0.f);
    out[(size_t)n * 64 + t] = v;
}

extern "C" void kernel_launch(void* const* d_in, const int* in_sizes, int n_in,
                              void* d_out, int out_size, void* d_ws, size_t ws_size,
                              hipStream_t stream)
{
    const float* d_features = (const float*)d_in[0];
    const float* g_features = (const float*)d_in[1];
    const float* miRNA_dis  = (const float*)d_in[2];
    const float* gene_dis   = (const float*)d_in[3];
    const float* Wd  = (const float*)d_in[4];
    const float* bd  = (const float*)d_in[5];
    const float* Wg  = (const float*)d_in[6];
    const float* bg  = (const float*)d_in[7];
    const float* W1  = (const float*)d_in[8];
    const float* W4  = (const float*)d_in[9];
    const float* Ws1 = (const float*)d_in[10];
    const float* Wn1 = (const float*)d_in[11];
    const float* b1  = (const float*)d_in[12];
    const float* Ws2 = (const float*)d_in[13];
    const float* Wn2 = (const float*)d_in[14];
    const float* b2  = (const float*)d_in[15];
    const int* src = (const int*)d_in[16];
    const int* dst = (const int*)d_in[17];
    (void)in_sizes; (void)n_in; (void)out_size; (void)ws_size;

    char* ws = (char*)d_ws;
    size_t off = 0;
    auto alloc = [&](size_t bytes) {
        void* p = ws + off;
        off = (off + bytes + 255) & ~(size_t)255;
        return p;
    };
    float* h0 = (float*)alloc((size_t)NTOT * EMB * 4);
    float* P  = (float*)alloc((size_t)NTOT * HID * 4);
    float* Q  = (float*)alloc((size_t)NTOT * HID * 4);
    float* h1 = (float*)alloc((size_t)NTOT * HID * 4);
    int* deg       = (int*)alloc((size_t)NTOT * 4);
    int* row_start = (int*)alloc((size_t)(NTOT + 1) * 4);
    int* cursor    = (int*)alloc((size_t)NTOT * 4);
    int* esrc      = (int*)alloc((size_t)EDG * 4);
    ushort* miT = (ushort*)alloc((size_t)NDIS * 2000 * 2);   // miRNA_dis^T bf16 [5000][2000]
    ushort* WdT = (ushort*)alloc((size_t)128 * 384 * 2);
    ushort* WgT = (ushort*)alloc((size_t)128 * 4400 * 2);
    ushort* W1T = (ushort*)alloc((size_t)128 * 2000 * 2);
    ushort* W4T = (ushort*)alloc((size_t)128 * 5000 * 2);

    // ---- CSR by dst ----
    hipMemsetAsync(deg, 0, (size_t)NTOT * 4, stream);
    k_deg<<<(EDG + 255) / 256, 256, 0, stream>>>(dst, deg, EDG);
    k_scan<<<1, 1024, 0, stream>>>(deg, row_start, cursor, NTOT);
    k_fill<<<(EDG + 255) / 256, 256, 0, stream>>>(src, dst, cursor, esrc, EDG);

    // ---- transpose/convert weights + miRNA ----
    k_tcvt<<<dim3(4, 12),  256, 0, stream>>>(Wd, WdT, 383, 128, 384);
    k_tcvt<<<dim3(4, 138), 256, 0, stream>>>(Wg, WgT, 4395, 128, 4400);
    k_tcvt<<<dim3(4, 63),  256, 0, stream>>>(W1, W1T, 2000, 128, 2000);
    k_tcvt<<<dim3(4, 157), 256, 0, stream>>>(W4, W4T, 5000, 128, 5000);
    k_tcvt<<<dim3(157, 63), 256, 0, stream>>>(miRNA_dis, miT, 2000, NDIS, 2000);

    // ---- node embeddings: h0 = 0.9*(X@W+b) + 0.1*(cross term) ----
    hipMemsetAsync(h0, 0, (size_t)NTOT * EMB * 4, stream);
    mfma_gemm<true><<<dim3(79, 2),  256, 0, stream>>>(d_features, WdT, h0, NDIS, 383, 384, 0.9f);
    mfma_gemm<false><<<dim3(79, 6), 256, 0, stream>>>(miT, W1T, h0, NDIS, 2000, 2000, 0.1f);
    mfma_gemm<true><<<dim3(313, 2), 256, 0, stream>>>(g_features, WgT, h0 + (size_t)NDIS * EMB, NGEN, 4395, 4400, 0.9f);
    mfma_gemm<true><<<dim3(313, 2), 256, 0, stream>>>(gene_dis, W4T, h0 + (size_t)NDIS * EMB, NGEN, 5000, 5000, 0.1f);
    k_bias<<<(NTOT * EMB + 255) / 256, 256, 0, stream>>>(h0, bd, bg);

    // ---- SAGE layer 1 ----
    k_proj<<<NTOT / 2, 256, 0, stream>>>(h0, EMB, Ws1, Wn1, b1, P, Q, NTOT);
    k_agg<<<NTOT, 64, 0, stream>>>(Q, P, row_start, esrc, h1, 1);

    // ---- SAGE layer 2 ----
    k_proj<<<NTOT / 2, 256, 0, stream>>>(h1, HID, Ws2, Wn2, b2, P, Q, NTOT);
    k_agg<<<NTOT, 64, 0, stream>>>(Q, P, row_start, esrc, (float*)d_out, 0);
}

// Round 3
// 426.113 us; speedup vs baseline: 6.2593x; 1.7250x over previous
//
#include <hip/hip_runtime.h>

#define NDIS 5000
#define NGEN 20000
#define NTOT 25000
#define EDG  400000

typedef __attribute__((ext_vector_type(8))) short short8;
typedef __attribute__((ext_vector_type(4))) float f32x4;
typedef __attribute__((ext_vector_type(4), aligned(4))) float f32x4u;

// ---------------- workspace layout (compile-time) ----------------
constexpr size_t AL(size_t x) { return (x + 255) & ~(size_t)255; }
constexpr size_t OFF_H0   = 0;
constexpr size_t OFF_PQ   = AL(OFF_H0  + (size_t)NTOT * 128 * 4);
constexpr size_t OFF_H1   = AL(OFF_PQ  + (size_t)NTOT * 128 * 4);
constexpr size_t OFF_DEG  = AL(OFF_H1  + (size_t)NTOT * 64 * 4);
constexpr size_t OFF_RS   = AL(OFF_DEG + (size_t)NTOT * 4);
constexpr size_t OFF_CUR  = AL(OFF_RS  + (size_t)(NTOT + 1) * 4);
constexpr size_t OFF_ESRC = AL(OFF_CUR + (size_t)NTOT * 4);
constexpr size_t OFF_MIT  = AL(OFF_ESRC + (size_t)EDG * 4);
constexpr size_t OFF_BDIS = AL(OFF_MIT + (size_t)5000 * 2016 * 2);
constexpr size_t OFF_BGEN = AL(OFF_BDIS + (size_t)128 * 2400 * 2);
constexpr size_t OFF_BS1  = AL(OFF_BGEN + (size_t)128 * 9440 * 2);
constexpr size_t OFF_BS2  = AL(OFF_BS1 + (size_t)128 * 128 * 2);

__device__ __forceinline__ ushort f2bf(float f) {
    unsigned u = __float_as_uint(f);
    u += 0x7fffu + ((u >> 16) & 1u);
    return (ushort)(u >> 16);
}

__device__ __forceinline__ void MFMA(f32x4& d, short8 a, short8 b) {
    asm volatile("v_mfma_f32_16x16x32_bf16 %0, %1, %2, %0"
                 : "+v"(d) : "v"(a), "v"(b));
}

// ---------------- multi-descriptor transpose+scale+cvt ----------------
// desc: in[R][C] f32 -> out[C][ld] bf16 (out[c*ld + r] = scale*in[r][c]),
// rows r in [R, Rp) written as 0 (pad), so GEMM B/A2-staging needs no guards.
struct TcvtIns { const float* p[9]; };

__global__ __launch_bounds__(256) void k_tcvt_multi(TcvtIns ins, char* ws)
{
    constexpr int   TRr[9] = {383, 2000, 4395, 5000, 2000, 128, 128, 64, 64};
    constexpr int   TCc[9] = {128, 128, 128, 128, 5000, 64, 64, 64, 64};
    constexpr int   TLD[9] = {2400, 2400, 9440, 9440, 2016, 128, 128, 64, 64};
    constexpr int   TRP[9] = {384, 2016, 4416, 5024, 2016, 128, 128, 64, 64};
    constexpr float TSC[9] = {0.9f, 0.1f, 0.9f, 0.1f, 1.f, 1.f, 1.f, 1.f, 1.f};
    constexpr size_t TOUT[9] = {OFF_BDIS, OFF_BDIS + 384 * 2, OFF_BGEN,
                                OFF_BGEN + (size_t)4416 * 2, OFF_MIT,
                                OFF_BS1, OFF_BS1 + (size_t)64 * 128 * 2,
                                OFF_BS2, OFF_BS2 + (size_t)64 * 64 * 2};
    constexpr int TNBX[9] = {4, 4, 4, 4, 157, 2, 2, 2, 2};
    constexpr int PRE[10] = {0, 48, 300, 852, 1480, 11371, 11379, 11387, 11391, 11395};

    int bid = blockIdx.x;
    int d = 0;
#pragma unroll
    for (int q = 1; q < 9; ++q) if (bid >= PRE[q]) d = q;
    int local = bid - PRE[d];
    int bx = local % TNBX[d], by = local / TNBX[d];
    const int R = TRr[d], C = TCc[d], ld = TLD[d], Rp = TRP[d];
    const float scale = TSC[d];
    const float* in = ins.p[d];
    ushort* out = (ushort*)(ws + TOUT[d]);

    __shared__ float t[32][33];
    int tx = threadIdx.x & 31, ty = threadIdx.x >> 5;
    int c0 = bx * 32, r0 = by * 32;
#pragma unroll
    for (int j = 0; j < 4; ++j) {
        int r = r0 + ty + j * 8, c = c0 + tx;
        t[ty + j * 8][tx] = (r < R && c < C) ? in[(size_t)r * C + c] : 0.f;
    }
    __syncthreads();
#pragma unroll
    for (int j = 0; j < 4; ++j) {
        int c = c0 + ty + j * 8, r = r0 + tx;
        if (c < C && r < Rp) out[(size_t)c * ld + r] = f2bf(scale * t[tx][ty + j * 8]);
    }
}

// ---------------- unified MFMA GEMM ----------------
// C[M,128] (+)= [A1(f32,K1 valid,K1p pad) | A2(K2 region)] @ Bt[128][ldB]^T
// Bt bf16, fully written (pads zeroed). ATOMIC: atomicAdd into pre-inited C,
// split-K over gridDim.y. !ATOMIC: direct store + bias on cols<64.
template<bool A2BF16, bool ATOMIC>
__global__ __launch_bounds__(256) void mfma_gemm(
    const float* __restrict__ A1, int lda1, int K1, int K1p,
    const void* __restrict__ A2, int lda2, int K2,
    const ushort* __restrict__ Bt, int ldB, int ktiles,
    float* __restrict__ C, int M, const float* __restrict__ bias)
{
    __shared__ ushort Alds[64 * 40];
    __shared__ ushort Blds[128 * 40];
    const int tid  = threadIdx.x;
    const int lane = tid & 63;
    const int w    = tid >> 6;
    const int wr = w >> 1, wc = w & 1;
    const int bm0 = blockIdx.x * 64;
    const int ar = tid >> 2, aq = tid & 3;
    const int br = tid >> 1, bh = tid & 1;

    const int per = (ktiles + gridDim.y - 1) / gridDim.y;
    const int kt0 = blockIdx.y * per;
    const int kt1 = min(ktiles, kt0 + per);
    if (kt0 >= kt1) return;

    f32x4 acc[2][4];
#pragma unroll
    for (int i = 0; i < 2; ++i)
#pragma unroll
        for (int j = 0; j < 4; ++j) acc[i][j] = {0.f, 0.f, 0.f, 0.f};

    const int arow = bm0 + ar;
    for (int kt = kt0; kt < kt1; ++kt) {
        const int kk = kt << 5;
        // ---- stage A ----
        {
            short8 s = {0, 0, 0, 0, 0, 0, 0, 0};
            if (arow < M) {
                int k = kk + aq * 8;
                if (k < K1p) {
                    const float* p = A1 + (size_t)arow * lda1 + k;
                    if (k + 8 <= K1) {
                        f32x4u v0 = *(const f32x4u*)p;
                        f32x4u v1 = *(const f32x4u*)(p + 4);
#pragma unroll
                        for (int e = 0; e < 4; ++e) {
                            s[e]     = (short)f2bf(v0[e]);
                            s[4 + e] = (short)f2bf(v1[e]);
                        }
                    } else {
#pragma unroll
                        for (int e = 0; e < 8; ++e)
                            s[e] = (short)f2bf((k + e < K1) ? p[e] : 0.f);
                    }
                } else {
                    int kc = k - K1p;
                    if (A2BF16) {
                        s = *(const short8*)((const ushort*)A2 + (size_t)arow * lda2 + kc);
                    } else {
                        const float* p = (const float*)A2 + (size_t)arow * lda2 + kc;
                        if (kc + 8 <= K2) {
                            f32x4u v0 = *(const f32x4u*)p;
                            f32x4u v1 = *(const f32x4u*)(p + 4);
#pragma unroll
                            for (int e = 0; e < 4; ++e) {
                                s[e]     = (short)f2bf(v0[e]);
                                s[4 + e] = (short)f2bf(v1[e]);
                            }
                        } else {
#pragma unroll
                            for (int e = 0; e < 8; ++e)
                                s[e] = (short)f2bf((kc + e < K2) ? p[e] : 0.f);
                        }
                    }
                }
            }
            *(short8*)&Alds[ar * 40 + aq * 8] = s;
        }
        // ---- stage B (ldB fully readable; pads are zeros) ----
        {
            const ushort* p = Bt + (size_t)br * ldB + kk + bh * 16;
            *(short8*)&Blds[br * 40 + bh * 16]     = *(const short8*)p;
            *(short8*)&Blds[br * 40 + bh * 16 + 8] = *(const short8*)(p + 8);
        }
        __syncthreads();
        {
            const int fr = lane & 15, kg = (lane >> 4) * 8;
            short8 a0 = *(const short8*)&Alds[(wr * 32 + fr) * 40 + kg];
            short8 a1 = *(const short8*)&Alds[(wr * 32 + 16 + fr) * 40 + kg];
            short8 b0 = *(const short8*)&Blds[(wc * 64 + fr) * 40 + kg];
            short8 b1 = *(const short8*)&Blds[(wc * 64 + 16 + fr) * 40 + kg];
            short8 b2 = *(const short8*)&Blds[(wc * 64 + 32 + fr) * 40 + kg];
            short8 b3 = *(const short8*)&Blds[(wc * 64 + 48 + fr) * 40 + kg];
            MFMA(acc[0][0], a0, b0); MFMA(acc[0][1], a0, b1);
            MFMA(acc[0][2], a0, b2); MFMA(acc[0][3], a0, b3);
            MFMA(acc[1][0], a1, b0); MFMA(acc[1][1], a1, b1);
            MFMA(acc[1][2], a1, b2); MFMA(acc[1][3], a1, b3);
        }
        __syncthreads();
    }
    asm volatile("s_nop 7\n\ts_nop 7\n\ts_nop 7" ::: "memory");
    const int fr = lane & 15, fq = lane >> 4;
#pragma unroll
    for (int mi = 0; mi < 2; ++mi)
#pragma unroll
        for (int ni = 0; ni < 4; ++ni)
#pragma unroll
            for (int r = 0; r < 4; ++r) {
                int row = bm0 + wr * 32 + mi * 16 + fq * 4 + r;
                if (row < M) {
                    int col = wc * 64 + ni * 16 + fr;
                    if (ATOMIC) {
                        atomicAdd(&C[(size_t)row * 128 + col], acc[mi][ni][r]);
                    } else {
                        float v = acc[mi][ni][r];
                        if (col < 64) v += bias[col];
                        C[(size_t)row * 128 + col] = v;
                    }
                }
            }
}

// ---------------- h0 init with scaled bias ----------------
__global__ void k_binit(float* __restrict__ h0, const float* __restrict__ bd,
                        const float* __restrict__ bg) {
    int i = blockIdx.x * 256 + threadIdx.x;
    if (i >= NTOT * 128) return;
    int col = i & 127;
    h0[i] = 0.9f * ((i >> 7) < NDIS ? bd[col] : bg[col]);
}

// ---------------- CSR build ----------------
__global__ void k_deg(const int* __restrict__ dst, int* __restrict__ deg, int E) {
    int e = blockIdx.x * blockDim.x + threadIdx.x;
    if (e < E) atomicAdd(&deg[dst[e]], 1);
}

__global__ __launch_bounds__(1024) void k_scan(const int* __restrict__ deg,
                                               int* __restrict__ row_start,
                                               int* __restrict__ cursor, int n) {
    __shared__ int wsum[16];
    __shared__ int carry_s;
    int t = threadIdx.x;
    int lane = t & 63, wid = t >> 6;
    if (t == 0) { carry_s = 0; row_start[0] = 0; }
    __syncthreads();
    for (int base = 0; base < n; base += 1024) {
        int i = base + t;
        int v = (i < n) ? deg[i] : 0;
        int x = v;
#pragma unroll
        for (int off = 1; off < 64; off <<= 1) {
            int y = __shfl_up(x, off, 64);
            if (lane >= off) x += y;
        }
        if (lane == 63) wsum[wid] = x;
        __syncthreads();
        if (wid == 0) {
            int s = (lane < 16) ? wsum[lane] : 0;
#pragma unroll
            for (int off = 1; off < 16; off <<= 1) {
                int y = __shfl_up(s, off, 64);
                if (lane >= off) s += y;
            }
            if (lane < 16) wsum[lane] = s;
        }
        __syncthreads();
        int pre = (wid > 0 ? wsum[wid - 1] : 0) + carry_s;
        int incl = x + pre;
        if (i < n) { row_start[i + 1] = incl; cursor[i] = incl - v; }
        __syncthreads();
        if (t == 1023) carry_s = incl;
        __syncthreads();
    }
}

__global__ void k_fill(const int* __restrict__ src, const int* __restrict__ dst,
                       int* __restrict__ cursor, int* __restrict__ esrc, int E) {
    int e = blockIdx.x * blockDim.x + threadIdx.x;
    if (e < E) {
        int pos = atomicAdd(&cursor[dst[e]], 1);
        esrc[pos] = src[e];
    }
}

// ---------------- aggregate: out[n] = (relu?) P[n] + mean_nbr Q ----------------
// PQ[n][0..63] = P (bias applied), PQ[n][64..127] = Q
__global__ __launch_bounds__(64) void k_agg(const float* __restrict__ PQ,
                                            const int* __restrict__ rs,
                                            const int* __restrict__ esrc,
                                            float* __restrict__ out, int relu)
{
    int n = blockIdx.x, t = threadIdx.x;
    int s0 = rs[n], s1 = rs[n + 1];
    float a0 = 0.f, a1 = 0.f, a2 = 0.f, a3 = 0.f;
    int i = s0;
    for (; i + 4 <= s1; i += 4) {
        int e0 = esrc[i], e1 = esrc[i + 1], e2 = esrc[i + 2], e3 = esrc[i + 3];
        a0 += PQ[(size_t)e0 * 128 + 64 + t];
        a1 += PQ[(size_t)e1 * 128 + 64 + t];
        a2 += PQ[(size_t)e2 * 128 + 64 + t];
        a3 += PQ[(size_t)e3 * 128 + 64 + t];
    }
    for (; i < s1; ++i) a0 += PQ[(size_t)esrc[i] * 128 + 64 + t];
    float s = (a0 + a1) + (a2 + a3);
    float dg = (float)(s1 - s0);
    s /= fmaxf(dg, 1.f);
    float v = PQ[(size_t)n * 128 + t] + s;
    if (relu) v = fmaxf(v, 0.f);
    out[(size_t)n * 64 + t] = v;
}

extern "C" void kernel_launch(void* const* d_in, const int* in_sizes, int n_in,
                              void* d_out, int out_size, void* d_ws, size_t ws_size,
                              hipStream_t stream)
{
    const float* d_features = (const float*)d_in[0];
    const float* g_features = (const float*)d_in[1];
    const float* miRNA_dis  = (const float*)d_in[2];
    const float* gene_dis   = (const float*)d_in[3];
    const float* Wd  = (const float*)d_in[4];
    const float* bd  = (const float*)d_in[5];
    const float* Wg  = (const float*)d_in[6];
    const float* bg  = (const float*)d_in[7];
    const float* W1  = (const float*)d_in[8];
    const float* W4  = (const float*)d_in[9];
    const float* Ws1 = (const float*)d_in[10];
    const float* Wn1 = (const float*)d_in[11];
    const float* b1  = (const float*)d_in[12];
    const float* Ws2 = (const float*)d_in[13];
    const float* Wn2 = (const float*)d_in[14];
    const float* b2  = (const float*)d_in[15];
    const int* src = (const int*)d_in[16];
    const int* dst = (const int*)d_in[17];
    (void)in_sizes; (void)n_in; (void)out_size; (void)ws_size;

    char* ws = (char*)d_ws;
    float*  h0   = (float*)(ws + OFF_H0);
    float*  PQ   = (float*)(ws + OFF_PQ);
    float*  h1   = (float*)(ws + OFF_H1);
    int*    deg  = (int*)(ws + OFF_DEG);
    int*    rs   = (int*)(ws + OFF_RS);
    int*    cur  = (int*)(ws + OFF_CUR);
    int*    esrc = (int*)(ws + OFF_ESRC);
    ushort* miT  = (ushort*)(ws + OFF_MIT);
    ushort* Bdis = (ushort*)(ws + OFF_BDIS);
    ushort* Bgen = (ushort*)(ws + OFF_BGEN);
    ushort* Bs1  = (ushort*)(ws + OFF_BS1);
    ushort* Bs2  = (ushort*)(ws + OFF_BS2);

    // ---- CSR by dst ----
    hipMemsetAsync(deg, 0, (size_t)NTOT * 4, stream);
    k_deg<<<(EDG + 255) / 256, 256, 0, stream>>>(dst, deg, EDG);
    k_scan<<<1, 1024, 0, stream>>>(deg, rs, cur, NTOT);
    k_fill<<<(EDG + 255) / 256, 256, 0, stream>>>(src, dst, cur, esrc, EDG);

    // ---- all transposes/converts in one launch ----
    TcvtIns ins;
    ins.p[0] = Wd;  ins.p[1] = W1;  ins.p[2] = Wg;  ins.p[3] = W4;
    ins.p[4] = miRNA_dis; ins.p[5] = Ws1; ins.p[6] = Wn1; ins.p[7] = Ws2; ins.p[8] = Wn2;
    k_tcvt_multi<<<11395, 256, 0, stream>>>(ins, ws);

    // ---- h0 = 0.9*bias, then fused embedding GEMMs (atomic split-K) ----
    k_binit<<<(NTOT * 128 + 255) / 256, 256, 0, stream>>>(h0, bd, bg);
    mfma_gemm<true, true><<<dim3(79, 4), 256, 0, stream>>>(
        d_features, 383, 383, 384, miT, 2016, 2016, Bdis, 2400, 75, h0, NDIS, nullptr);
    mfma_gemm<false, true><<<dim3(313, 4), 256, 0, stream>>>(
        g_features, 4395, 4395, 4416, gene_dis, 5000, 5000, Bgen, 9440, 295,
        h0 + (size_t)NDIS * 128, NGEN, nullptr);

    // ---- SAGE layer 1: PQ = h0 @ [Ws1|Wn1] (+b1 on P), then aggregate ----
    mfma_gemm<false, false><<<dim3(391, 1), 256, 0, stream>>>(
        h0, 128, 128, 128, nullptr, 0, 0, Bs1, 128, 4, PQ, NTOT, b1);
    k_agg<<<NTOT, 64, 0, stream>>>(PQ, rs, esrc, h1, 1);

    // ---- SAGE layer 2 ----
    mfma_gemm<false, false><<<dim3(391, 1), 256, 0, stream>>>(
        h1, 64, 64, 64, nullptr, 0, 0, Bs2, 64, 2, PQ, NTOT, b2);
    k_agg<<<NTOT, 64, 0, stream>>>(PQ, rs, esrc, (float*)d_out, 0);
}

// Round 4
// 410.726 us; speedup vs baseline: 6.4938x; 1.0375x over previous
//
#include <hip/hip_runtime.h>

#define NDIS 5000
#define NGEN 20000
#define NTOT 25000
#define EDG  400000

typedef __attribute__((ext_vector_type(8))) short short8;
typedef __attribute__((ext_vector_type(4))) float f32x4;
typedef __attribute__((ext_vector_type(4), aligned(4))) float f32x4u;

// ---------------- workspace layout (compile-time) ----------------
constexpr size_t AL(size_t x) { return (x + 255) & ~(size_t)255; }
constexpr size_t OFF_H0   = 0;
constexpr size_t OFF_PQ   = AL(OFF_H0  + (size_t)NTOT * 128 * 4);
constexpr size_t OFF_H1   = AL(OFF_PQ  + (size_t)NTOT * 128 * 4);
constexpr size_t OFF_DEG  = AL(OFF_H1  + (size_t)NTOT * 64 * 4);
constexpr size_t OFF_RS   = AL(OFF_DEG + (size_t)NTOT * 4);
constexpr size_t OFF_CUR  = AL(OFF_RS  + (size_t)(NTOT + 1) * 4);
constexpr size_t OFF_ESRC = AL(OFF_CUR + (size_t)NTOT * 4);
constexpr size_t OFF_MIT  = AL(OFF_ESRC + (size_t)EDG * 4);
constexpr size_t OFF_BDIS = AL(OFF_MIT + (size_t)5000 * 2048 * 2);
constexpr size_t OFF_BGEN = AL(OFF_BDIS + (size_t)128 * 2432 * 2);
constexpr size_t OFF_BS1  = AL(OFF_BGEN + (size_t)128 * 9472 * 2);
constexpr size_t OFF_BS2  = AL(OFF_BS1 + (size_t)128 * 128 * 2);

__device__ __forceinline__ ushort f2bf(float f) {
    unsigned u = __float_as_uint(f);
    u += 0x7fffu + ((u >> 16) & 1u);
    return (ushort)(u >> 16);
}

__device__ __forceinline__ void MFMA(f32x4& d, short8 a, short8 b) {
    asm volatile("v_mfma_f32_16x16x32_bf16 %0, %1, %2, %0"
                 : "+v"(d) : "v"(a), "v"(b));
}

// ---------------- multi-descriptor transpose+scale+cvt ----------------
// out[c*ld + r] = scale*in[r][c]; rows r in [R, Rp) written as 0 (pad).
struct TcvtIns { const float* p[9]; };

__global__ __launch_bounds__(256) void k_tcvt_multi(TcvtIns ins, char* ws)
{
    constexpr int   TRr[9] = {383, 2000, 4395, 5000, 2000, 128, 128, 64, 64};
    constexpr int   TCc[9] = {128, 128, 128, 128, 5000, 64, 64, 64, 64};
    constexpr int   TLD[9] = {2432, 2432, 9472, 9472, 2048, 128, 128, 64, 64};
    constexpr int   TRP[9] = {384, 2048, 4416, 5056, 2048, 128, 128, 64, 64};
    constexpr float TSC[9] = {0.9f, 0.1f, 0.9f, 0.1f, 1.f, 1.f, 1.f, 1.f, 1.f};
    constexpr size_t TOUT[9] = {OFF_BDIS, OFF_BDIS + (size_t)384 * 2, OFF_BGEN,
                                OFF_BGEN + (size_t)4416 * 2, OFF_MIT,
                                OFF_BS1, OFF_BS1 + (size_t)64 * 128 * 2,
                                OFF_BS2, OFF_BS2 + (size_t)64 * 64 * 2};
    constexpr int TNBX[9] = {4, 4, 4, 4, 157, 2, 2, 2, 2};
    constexpr int PRE[10] = {0, 48, 304, 856, 1488, 11536, 11544, 11552, 11556, 11560};

    int bid = blockIdx.x;
    int d = 0;
#pragma unroll
    for (int q = 1; q < 9; ++q) if (bid >= PRE[q]) d = q;
    int local = bid - PRE[d];
    int bx = local % TNBX[d], by = local / TNBX[d];
    const int R = TRr[d], C = TCc[d], ld = TLD[d], Rp = TRP[d];
    const float scale = TSC[d];
    const float* in = ins.p[d];
    ushort* out = (ushort*)(ws + TOUT[d]);

    __shared__ float t[32][33];
    int tx = threadIdx.x & 31, ty = threadIdx.x >> 5;
    int c0 = bx * 32, r0 = by * 32;
#pragma unroll
    for (int j = 0; j < 4; ++j) {
        int r = r0 + ty + j * 8, c = c0 + tx;
        t[ty + j * 8][tx] = (r < R && c < C) ? in[(size_t)r * C + c] : 0.f;
    }
    __syncthreads();
#pragma unroll
    for (int j = 0; j < 4; ++j) {
        int c = c0 + ty + j * 8, r = r0 + tx;
        if (c < C && r < Rp) out[(size_t)c * ld + r] = f2bf(scale * t[tx][ty + j * 8]);
    }
}

// ---------------- pipelined MFMA GEMM ----------------
// C[M,128] (+)= [A1(f32, K1 valid, K1p pad) | A2(K2 region)] @ Bt[128][ldB]^T
// BK=64; 2-phase reg-staged pipeline with raw barriers (prefetch loads stay
// in flight across barriers). K1p must be a multiple of 64; Bt fully padded.
template<bool A2BF16, bool ATOMIC>
__global__ __launch_bounds__(256) void mfma_gemm(
    const float* __restrict__ A1, int lda1, int K1, int K1p,
    const void* __restrict__ A2, int lda2, int K2,
    const ushort* __restrict__ Bt, int ldB, int ktiles,
    float* __restrict__ C, int M, const float* __restrict__ bias)
{
    __shared__ ushort Alds[64 * 72];
    __shared__ ushort Blds[128 * 72];
    const int tid  = threadIdx.x;
    const int lane = tid & 63;
    const int w    = tid >> 6;
    const int wr = w >> 1, wc = w & 1;
    const int bm0 = blockIdx.x * 64;
    const int ar = tid >> 2, aks = (tid & 3) * 16;  // A: 16 k per thread
    const int br = tid >> 1, bks = (tid & 1) * 32;  // B: 32 k per thread

    const int per = (ktiles + gridDim.y - 1) / gridDim.y;
    const int kt0 = blockIdx.y * per;
    const int kt1 = min(ktiles, kt0 + per);
    if (kt0 >= kt1) return;

    f32x4 acc[2][4];
#pragma unroll
    for (int i = 0; i < 2; ++i)
#pragma unroll
        for (int j = 0; j < 4; ++j) acc[i][j] = {0.f, 0.f, 0.f, 0.f};

    const int arow = bm0 + ar;

    float  fa0[16], fa1[16];
    short8 sa0[2],  sa1[2];
    short8 sb0[4],  sb1[4];

    auto loadA = [&](int kt, float* fa, short8* sa) {
        if (arow >= M) return;
        const int kkb = kt << 6;
#pragma unroll
        for (int s = 0; s < 2; ++s) {
            const int k = kkb + aks + s * 8;
            if (k < K1p) {
                const float* p = A1 + (size_t)arow * lda1 + k;
                if (k + 8 <= K1) {
                    f32x4u v0 = *(const f32x4u*)p;
                    f32x4u v1 = *(const f32x4u*)(p + 4);
#pragma unroll
                    for (int e = 0; e < 4; ++e) { fa[s*8+e] = v0[e]; fa[s*8+4+e] = v1[e]; }
                } else {
#pragma unroll
                    for (int e = 0; e < 8; ++e) fa[s*8+e] = (k + e < K1) ? p[e] : 0.f;
                }
            } else {
                const int kc = k - K1p;
                if (A2BF16) {
                    sa[s] = *(const short8*)((const ushort*)A2 + (size_t)arow * lda2 + kc);
                } else {
                    const float* p = (const float*)A2 + (size_t)arow * lda2 + kc;
                    if (kc + 8 <= K2) {
                        f32x4u v0 = *(const f32x4u*)p;
                        f32x4u v1 = *(const f32x4u*)(p + 4);
#pragma unroll
                        for (int e = 0; e < 4; ++e) { fa[s*8+e] = v0[e]; fa[s*8+4+e] = v1[e]; }
                    } else {
#pragma unroll
                        for (int e = 0; e < 8; ++e) fa[s*8+e] = (kc + e < K2) ? p[e] : 0.f;
                    }
                }
            }
        }
    };
    auto loadB = [&](int kt, short8* sb) {
        const ushort* p = Bt + (size_t)br * ldB + (kt << 6) + bks;
#pragma unroll
        for (int s = 0; s < 4; ++s) sb[s] = *(const short8*)(p + s * 8);
    };
    auto writeT = [&](int kt, const float* fa, const short8* sa, const short8* sb) {
        const int kkb = kt << 6;
#pragma unroll
        for (int s = 0; s < 2; ++s) {
            short8 v;
            if (A2BF16 && (kkb + aks + s * 8) >= K1p) {
                v = sa[s];
            } else {
#pragma unroll
                for (int e = 0; e < 8; ++e) v[e] = (short)f2bf(fa[s * 8 + e]);
            }
            *(short8*)&Alds[ar * 72 + aks + s * 8] = v;
        }
#pragma unroll
        for (int s = 0; s < 4; ++s)
            *(short8*)&Blds[br * 72 + bks + s * 8] = sb[s];
    };
    auto compute = [&]() {
        const int fr = lane & 15;
        const int kq = (lane >> 4) * 8;
#pragma unroll
        for (int ks2 = 0; ks2 < 2; ++ks2) {
            const int ko = ks2 * 32 + kq;
            short8 a0 = *(const short8*)&Alds[(wr * 32 +      fr) * 72 + ko];
            short8 a1 = *(const short8*)&Alds[(wr * 32 + 16 + fr) * 72 + ko];
            short8 b0 = *(const short8*)&Blds[(wc * 64 +      fr) * 72 + ko];
            short8 b1 = *(const short8*)&Blds[(wc * 64 + 16 + fr) * 72 + ko];
            short8 b2 = *(const short8*)&Blds[(wc * 64 + 32 + fr) * 72 + ko];
            short8 b3 = *(const short8*)&Blds[(wc * 64 + 48 + fr) * 72 + ko];
            MFMA(acc[0][0], a0, b0); MFMA(acc[0][1], a0, b1);
            MFMA(acc[0][2], a0, b2); MFMA(acc[0][3], a0, b3);
            MFMA(acc[1][0], a1, b0); MFMA(acc[1][1], a1, b1);
            MFMA(acc[1][2], a1, b2); MFMA(acc[1][3], a1, b3);
        }
    };

    loadA(kt0, fa0, sa0); loadB(kt0, sb0);
    int kt = kt0;
    while (true) {
        __builtin_amdgcn_s_barrier();               // LDS free (prev compute done)
        writeT(kt, fa0, sa0, sb0);                  // vmcnt wait inserted on reg use
        if (kt + 1 < kt1) { loadA(kt + 1, fa1, sa1); loadB(kt + 1, sb1); }
        asm volatile("s_waitcnt lgkmcnt(0)" ::: "memory");  // ds_writes landed
        __builtin_amdgcn_s_barrier();               // LDS ready; prefetch stays in flight
        compute();
        if (++kt >= kt1) break;

        __builtin_amdgcn_s_barrier();
        writeT(kt, fa1, sa1, sb1);
        if (kt + 1 < kt1) { loadA(kt + 1, fa0, sa0); loadB(kt + 1, sb0); }
        asm volatile("s_waitcnt lgkmcnt(0)" ::: "memory");
        __builtin_amdgcn_s_barrier();
        compute();
        if (++kt >= kt1) break;
    }

    asm volatile("s_nop 7\n\ts_nop 7\n\ts_nop 7" ::: "memory");
    const int fr = lane & 15, fq = lane >> 4;
#pragma unroll
    for (int mi = 0; mi < 2; ++mi)
#pragma unroll
        for (int ni = 0; ni < 4; ++ni)
#pragma unroll
            for (int r = 0; r < 4; ++r) {
                int row = bm0 + wr * 32 + mi * 16 + fq * 4 + r;
                if (row < M) {
                    int col = wc * 64 + ni * 16 + fr;
                    if (ATOMIC) {
                        atomicAdd(&C[(size_t)row * 128 + col], acc[mi][ni][r]);
                    } else {
                        float v = acc[mi][ni][r];
                        if (col < 64) v += bias[col];
                        C[(size_t)row * 128 + col] = v;
                    }
                }
            }
}

// ---------------- h0 init with scaled bias ----------------
__global__ void k_binit(float* __restrict__ h0, const float* __restrict__ bd,
                        const float* __restrict__ bg) {
    int i = blockIdx.x * 256 + threadIdx.x;
    if (i >= NTOT * 128) return;
    int col = i & 127;
    h0[i] = 0.9f * ((i >> 7) < NDIS ? bd[col] : bg[col]);
}

// ---------------- CSR build ----------------
__global__ void k_deg(const int* __restrict__ dst, int* __restrict__ deg, int E) {
    int e = blockIdx.x * blockDim.x + threadIdx.x;
    if (e < E) atomicAdd(&deg[dst[e]], 1);
}

__global__ __launch_bounds__(1024) void k_scan(const int* __restrict__ deg,
                                               int* __restrict__ row_start,
                                               int* __restrict__ cursor, int n) {
    __shared__ int wsum[16];
    __shared__ int carry_s;
    int t = threadIdx.x;
    int lane = t & 63, wid = t >> 6;
    if (t == 0) { carry_s = 0; row_start[0] = 0; }
    __syncthreads();
    for (int base = 0; base < n; base += 1024) {
        int i = base + t;
        int v = (i < n) ? deg[i] : 0;
        int x = v;
#pragma unroll
        for (int off = 1; off < 64; off <<= 1) {
            int y = __shfl_up(x, off, 64);
            if (lane >= off) x += y;
        }
        if (lane == 63) wsum[wid] = x;
        __syncthreads();
        if (wid == 0) {
            int s = (lane < 16) ? wsum[lane] : 0;
#pragma unroll
            for (int off = 1; off < 16; off <<= 1) {
                int y = __shfl_up(s, off, 64);
                if (lane >= off) s += y;
            }
            if (lane < 16) wsum[lane] = s;
        }
        __syncthreads();
        int pre = (wid > 0 ? wsum[wid - 1] : 0) + carry_s;
        int incl = x + pre;
        if (i < n) { row_start[i + 1] = incl; cursor[i] = incl - v; }
        __syncthreads();
        if (t == 1023) carry_s = incl;
        __syncthreads();
    }
}

__global__ void k_fill(const int* __restrict__ src, const int* __restrict__ dst,
                       int* __restrict__ cursor, int* __restrict__ esrc, int E) {
    int e = blockIdx.x * blockDim.x + threadIdx.x;
    if (e < E) {
        int pos = atomicAdd(&cursor[dst[e]], 1);
        esrc[pos] = src[e];
    }
}

// ---------------- aggregate: out[n] = (relu?) P[n] + mean_nbr Q ----------------
__global__ __launch_bounds__(64) void k_agg(const float* __restrict__ PQ,
                                            const int* __restrict__ rs,
                                            const int* __restrict__ esrc,
                                            float* __restrict__ out, int relu)
{
    int n = blockIdx.x, t = threadIdx.x;
    int s0 = rs[n], s1 = rs[n + 1];
    float a0 = 0.f, a1 = 0.f, a2 = 0.f, a3 = 0.f;
    int i = s0;
    for (; i + 4 <= s1; i += 4) {
        int e0 = esrc[i], e1 = esrc[i + 1], e2 = esrc[i + 2], e3 = esrc[i + 3];
        a0 += PQ[(size_t)e0 * 128 + 64 + t];
        a1 += PQ[(size_t)e1 * 128 + 64 + t];
        a2 += PQ[(size_t)e2 * 128 + 64 + t];
        a3 += PQ[(size_t)e3 * 128 + 64 + t];
    }
    for (; i < s1; ++i) a0 += PQ[(size_t)esrc[i] * 128 + 64 + t];
    float s = (a0 + a1) + (a2 + a3);
    float dg = (float)(s1 - s0);
    s /= fmaxf(dg, 1.f);
    float v = PQ[(size_t)n * 128 + t] + s;
    if (relu) v = fmaxf(v, 0.f);
    out[(size_t)n * 64 + t] = v;
}

extern "C" void kernel_launch(void* const* d_in, const int* in_sizes, int n_in,
                              void* d_out, int out_size, void* d_ws, size_t ws_size,
                              hipStream_t stream)
{
    const float* d_features = (const float*)d_in[0];
    const float* g_features = (const float*)d_in[1];
    const float* miRNA_dis  = (const float*)d_in[2];
    const float* gene_dis   = (const float*)d_in[3];
    const float* Wd  = (const float*)d_in[4];
    const float* bd  = (const float*)d_in[5];
    const float* Wg  = (const float*)d_in[6];
    const float* bg  = (const float*)d_in[7];
    const float* W1  = (const float*)d_in[8];
    const float* W4  = (const float*)d_in[9];
    const float* Ws1 = (const float*)d_in[10];
    const float* Wn1 = (const float*)d_in[11];
    const float* b1  = (const float*)d_in[12];
    const float* Ws2 = (const float*)d_in[13];
    const float* Wn2 = (const float*)d_in[14];
    const float* b2  = (const float*)d_in[15];
    const int* src = (const int*)d_in[16];
    const int* dst = (const int*)d_in[17];
    (void)in_sizes; (void)n_in; (void)out_size; (void)ws_size;

    char* ws = (char*)d_ws;
    float*  h0   = (float*)(ws + OFF_H0);
    float*  PQ   = (float*)(ws + OFF_PQ);
    float*  h1   = (float*)(ws + OFF_H1);
    int*    deg  = (int*)(ws + OFF_DEG);
    int*    rs   = (int*)(ws + OFF_RS);
    int*    cur  = (int*)(ws + OFF_CUR);
    int*    esrc = (int*)(ws + OFF_ESRC);
    ushort* miT  = (ushort*)(ws + OFF_MIT);
    ushort* Bdis = (ushort*)(ws + OFF_BDIS);
    ushort* Bgen = (ushort*)(ws + OFF_BGEN);
    ushort* Bs1  = (ushort*)(ws + OFF_BS1);
    ushort* Bs2  = (ushort*)(ws + OFF_BS2);

    // ---- CSR by dst ----
    hipMemsetAsync(deg, 0, (size_t)NTOT * 4, stream);
    k_deg<<<(EDG + 255) / 256, 256, 0, stream>>>(dst, deg, EDG);
    k_scan<<<1, 1024, 0, stream>>>(deg, rs, cur, NTOT);
    k_fill<<<(EDG + 255) / 256, 256, 0, stream>>>(src, dst, cur, esrc, EDG);

    // ---- all transposes/converts in one launch ----
    TcvtIns ins;
    ins.p[0] = Wd;  ins.p[1] = W1;  ins.p[2] = Wg;  ins.p[3] = W4;
    ins.p[4] = miRNA_dis; ins.p[5] = Ws1; ins.p[6] = Wn1; ins.p[7] = Ws2; ins.p[8] = Wn2;
    k_tcvt_multi<<<11560, 256, 0, stream>>>(ins, ws);

    // ---- h0 = 0.9*bias, then fused embedding GEMMs (atomic split-K) ----
    k_binit<<<(NTOT * 128 + 255) / 256, 256, 0, stream>>>(h0, bd, bg);
    mfma_gemm<true, true><<<dim3(79, 4), 256, 0, stream>>>(
        d_features, 383, 383, 384, miT, 2048, 2048, Bdis, 2432, 38, h0, NDIS, nullptr);
    mfma_gemm<false, true><<<dim3(313, 4), 256, 0, stream>>>(
        g_features, 4395, 4395, 4416, gene_dis, 5000, 5000, Bgen, 9472, 148,
        h0 + (size_t)NDIS * 128, NGEN, nullptr);

    // ---- SAGE layer 1: PQ = h0 @ [Ws1|Wn1] (+b1 on P), then aggregate ----
    mfma_gemm<false, false><<<dim3(391, 1), 256, 0, stream>>>(
        h0, 128, 128, 128, nullptr, 0, 0, Bs1, 128, 2, PQ, NTOT, b1);
    k_agg<<<NTOT, 64, 0, stream>>>(PQ, rs, esrc, h1, 1);

    // ---- SAGE layer 2 ----
    mfma_gemm<false, false><<<dim3(391, 1), 256, 0, stream>>>(
        h1, 64, 64, 64, nullptr, 0, 0, Bs2, 64, 1, PQ, NTOT, b2);
    k_agg<<<NTOT, 64, 0, stream>>>(PQ, rs, esrc, (float*)d_out, 0);
}